// Round 14
// baseline (1317.320 us; speedup 1.0000x reference)
//
#include <hip/hip_runtime.h>
#include <float.h>
#include <math.h>

#define BATCH 8
#define NPTS  2048
#define KNN   20
#define BN    (BATCH*NPTS)
#define SLOPE 0.2f
#define BNEPS 1e-5f

// ---------------- xx: per-point squared norm ----------------
__global__ void xx_kernel(const float* __restrict__ x, float* __restrict__ xx, int C) {
    int p = blockIdx.x * 256 + threadIdx.x;           // p in [0, BN)
    int b = p >> 11, n = p & (NPTS - 1);
    const float* xb = x + (size_t)b * C * NPTS;
    float s = 0.f;
    for (int c = 0; c < C; ++c) { float v = xb[(size_t)c * NPTS + n]; s = fmaf(v, v, s); }
    xx[p] = s;
}

// async global->LDS, 16B per lane (dest linear in lane order; proven knn6-13)
__device__ __forceinline__ void gload_lds16(const float* g, float* l) {
    __builtin_amdgcn_global_load_lds(
        (const __attribute__((address_space(1))) void*)g,
        (__attribute__((address_space(3))) void*)l, 16, 0, 0);
}

// ---------------- kNN v13: pool-collect + exact rank ----------------------
// 7 designs pinned at 210-225us: the per-thread sorted-insert is wave-gated
// (gate = 1-(1-p)^64 stays ~0.5-0.9 at 1% selectivity regardless of thr).
// knn13 removes the list from the hot scan entirely:
//   A: chunks 0-7 (512-col sample): value-only top-20 (2-op bubble) ->
//      16-way merge -> Trow = exact T20(sample) >= T20(full row).
//   B: all 32 chunks: recompute v BITWISE-IDENTICALLY (shared dist2x2),
//      v <= Trow -> rare LDS-atomic append (v,j) to per-row pool
//      (E~80, sigma~20, CAP=192 = +5.6 sigma; count is data-deterministic).
//   Emit: lex rank (v,i) over pool == lax.top_k order (knn9-proven exact,
//      order-independent -> deterministic despite atomic slot assignment).
template<int C>
__device__ __forceinline__ void dist2x2(const float (*xrT)[16], const float* xcb,
                                        const float* __restrict__ xxb, int j0,
                                        int ty2, int tx2,
                                        float& v00, float& v01, float& v10, float& v11) {
    float a00 = 0.f, a01 = 0.f, a10 = 0.f, a11 = 0.f;
#pragma unroll 4
    for (int c = 0; c < C; ++c) {
        float2 rv = *(const float2*)&xrT[c][ty2];
        float2 cv = *(const float2*)&xcb[c * 64 + tx2];
        a00 = fmaf(rv.x, cv.x, a00); a01 = fmaf(rv.x, cv.y, a01);
        a10 = fmaf(rv.y, cv.x, a10); a11 = fmaf(rv.y, cv.y, a11);
    }
    float2 xq = *(const float2*)&xxb[j0 + tx2];
    v00 = xq.x - 2.f * a00; v01 = xq.y - 2.f * a01;
    v10 = xq.x - 2.f * a10; v11 = xq.y - 2.f * a11;
}

template<int C>
__global__ __launch_bounds__(256, 2) void knn13_kernel(const float* __restrict__ x,
                                                       const float* __restrict__ xx,
                                                       int* __restrict__ idx) {
    constexpr int ROWS = 16, CHUNK = 64, NCH = NPTS / CHUNK;  // 32 chunks
    constexpr int SCH  = 8;                                   // sample chunks (512 cols)
    constexpr int CAP  = 192;
    constexpr int NST  = (C * 16 + 255) / 256;                // gload calls/thread

    __shared__ __align__(16) float xrT[C][16];
    __shared__ __align__(16) float xcb[2][C][CHUNK];          // dbuf
    __shared__ float Trow[ROWS];
    __shared__ int   cnt[ROWS];
    __shared__ __align__(16) union UU {
        struct { float dt[ROWS][65]; float Lv[16][KNN][ROWS]; } a;      // 24640 B
        struct { float pv[ROWS][CAP + 1]; unsigned short pj[ROWS][CAP + 2]; } b;
    } u;

    const int t  = threadIdx.x;
    const int b  = blockIdx.x >> 7;           // 128 tiles per batch
    const int r0 = (blockIdx.x & 127) * ROWS;
    const float* xb  = x  + (size_t)b * C * NPTS;
    const float* xxb = xx + (size_t)b * NPTS;

    const int ty = t >> 5, tx = t & 31;       // compute: rows 2ty..+1, cols 2tx..+1
    const int ty2 = ty * 2, tx2 = tx * 2;
    const int ry0 = ty2, ry1 = ty2 + 1;
    const int sr = t & 15, sg = t >> 4;       // scan: row sr, group sg (4 cols/chunk)

    // stage xrT
    for (int f = t; f < ROWS * C; f += 256) {
        int c = f >> 4, rr = f & 15;
        xrT[c][rr] = xb[(size_t)c * NPTS + r0 + rr];
    }

    // macro-free stage helper (lambda): chunk ch -> buffer bf
    auto stage = [&](int bf, int ch) {
#pragma unroll
        for (int k = 0; k < NST; ++k) {
            int i = t + 256 * k;
            if (i < C * 16) {
                int c = i >> 4, jq = i & 15;
                gload_lds16(xb + (size_t)c * NPTS + ch * CHUNK + jq * 4,
                            &xcb[bf][0][0] + (size_t)i * 4);
            }
        }
    };

    // ---------------- phase A: value-only top-20 over sample ----------------
    float lv[KNN];
#pragma unroll
    for (int s = 0; s < KNN; ++s) lv[s] = FLT_MAX;

    stage(0, 0);
    __syncthreads();                          // xrT + chunk 0 ready

    int cur = 0;
    for (int ch = 0; ch < SCH; ++ch) {
        if (ch + 1 < SCH) stage(cur ^ 1, ch + 1);
        float v00, v01, v10, v11;
        dist2x2<C>(xrT, &xcb[cur][0][0], xxb, ch * CHUNK, ty2, tx2, v00, v01, v10, v11);
        u.a.dt[ry0][tx2]     = v00; u.a.dt[ry0][tx2 + 1] = v01;
        u.a.dt[ry1][tx2]     = v10; u.a.dt[ry1][tx2 + 1] = v11;
        __syncthreads();                      // dt visible; next buf loaded

        // value-only scan: row sr, cols sg*4..+3
#pragma unroll
        for (int m = 0; m < 4; ++m) {
            float v = u.a.dt[sr][sg * 4 + m];
            if (v < lv[KNN - 1]) {
                lv[KNN - 1] = v;
#pragma unroll
                for (int s = KNN - 1; s > 0; --s) {
                    float lo = fminf(lv[s - 1], lv[s]);
                    float hi = fmaxf(lv[s - 1], lv[s]);
                    lv[s - 1] = lo; lv[s] = hi;
                }
            }
        }
        __syncthreads();                      // scan done before dt overwrite
        cur ^= 1;
    }

    // dump value lists + 16-way merge -> exact T20(sample) per row
#pragma unroll
    for (int s = 0; s < KNN; ++s) u.a.Lv[sg][s][sr] = lv[s];
    __syncthreads();
    if (t < ROWS) {
        float hv[16]; int pp[16];
#pragma unroll
        for (int g = 0; g < 16; ++g) { pp[g] = 0; hv[g] = u.a.Lv[g][0][t]; }
        float T = FLT_MAX;
        for (int o = 0; o < KNN; ++o) {
            float bv = hv[0]; int bg = 0;
#pragma unroll
            for (int g = 1; g < 16; ++g) if (hv[g] < bv) { bv = hv[g]; bg = g; }
            T = bv;
            ++pp[bg];
            hv[bg] = (pp[bg] < KNN) ? u.a.Lv[bg][pp[bg]][t] : FLT_MAX;
        }
        Trow[t] = T;
        cnt[t]  = 0;
    }
    __syncthreads();                          // Trow/cnt ready; Lv/dt dead

    const float T0 = Trow[ry0], T1 = Trow[ry1];

    // ---------------- phase B: full scan, pool-append (no bubble) ----------
    stage(0, 0);
    __syncthreads();
    cur = 0;
    for (int ch = 0; ch < NCH; ++ch) {
        if (ch + 1 < NCH) stage(cur ^ 1, ch + 1);
        float v00, v01, v10, v11;
        dist2x2<C>(xrT, &xcb[cur][0][0], xxb, ch * CHUNK, ty2, tx2, v00, v01, v10, v11);
        int j0 = ch * CHUNK + tx2;
        if (v00 <= T0) {
            int sl = atomicAdd(&cnt[ry0], 1);
            if (sl < CAP) { u.b.pv[ry0][sl] = v00; u.b.pj[ry0][sl] = (unsigned short)j0; }
        }
        if (v01 <= T0) {
            int sl = atomicAdd(&cnt[ry0], 1);
            if (sl < CAP) { u.b.pv[ry0][sl] = v01; u.b.pj[ry0][sl] = (unsigned short)(j0 + 1); }
        }
        if (v10 <= T1) {
            int sl = atomicAdd(&cnt[ry1], 1);
            if (sl < CAP) { u.b.pv[ry1][sl] = v10; u.b.pj[ry1][sl] = (unsigned short)j0; }
        }
        if (v11 <= T1) {
            int sl = atomicAdd(&cnt[ry1], 1);
            if (sl < CAP) { u.b.pv[ry1][sl] = v11; u.b.pj[ry1][sl] = (unsigned short)(j0 + 1); }
        }
        __syncthreads();                      // next buf ready; buf reads done
        cur ^= 1;
    }

    // ---------------- rank emit: lex (v,i) rank == lax.top_k order ---------
    {
        int rr = t & 15, role = t >> 4;
        int P = min(cnt[rr], CAP);
        int* op = idx + (size_t)(b * NPTS + r0 + rr) * KNN;
        for (int s = role; s < P; s += 16) {
            float vs = u.b.pv[rr][s]; int js = u.b.pj[rr][s];
            int rank = 0;
            for (int q = 0; q < P; ++q) {
                float vq = u.b.pv[rr][q]; int jq = u.b.pj[rr][q];
                rank += (vq < vs || (vq == vs && jq < js)) ? 1 : 0;
            }
            if (rank < KNN) op[rank] = js;
        }
    }
}

// ---------------- projection: y = x@Wtop, z = x@(Wbot-Wtop) ----------------
__global__ void proj_kernel(const float* __restrict__ x, const float* __restrict__ W,
                            float* __restrict__ y, float* __restrict__ z, int C, int Cout) {
    int p = blockIdx.x;
    int b = p >> 11, n = p & (NPTS - 1);
    int j = threadIdx.x;                      // j < Cout
    __shared__ float xc[64];
    if (j < C) xc[j] = x[(size_t)b * C * NPTS + (size_t)j * NPTS + n];
    __syncthreads();
    float sy = 0.f, sz = 0.f;
    for (int c = 0; c < C; ++c) {
        float xv = xc[c];
        float wt = W[c * Cout + j];
        float wb = W[(C + c) * Cout + j];
        sy = fmaf(xv, wt, sy);
        sz = fmaf(xv, wb - wt, sz);
    }
    y[(size_t)p * Cout + j] = sy;
    z[(size_t)p * Cout + j] = sz;
}

// ---------------- fused attention: one wave per point ----------------
template<int CO>
__global__ __launch_bounds__(256) void attn_kernel(const float* __restrict__ y,
                                                   const float* __restrict__ z,
                                                   const int* __restrict__ idx,
                                                   const float* __restrict__ a,
                                                   float* __restrict__ hout) {
    constexpr int NCH = CO / 64;
    constexpr int H   = CO / 4;
    int wv = threadIdx.x >> 6;
    int l  = threadIdx.x & 63;
    int p  = blockIdx.x * 4 + wv;             // b*N + n
    int b  = p >> 11;
    float hw[NCH][KNN], lg[NCH][KNN], zv[NCH], av[NCH];
#pragma unroll
    for (int q = 0; q < NCH; ++q) {
        int c = l + 64 * q;
        zv[q] = z[(size_t)p * CO + c];
        av[q] = a[(c & 3) * H + (c >> 2)];
    }
    const int* ip = idx + (size_t)p * KNN;
#pragma unroll
    for (int j = 0; j < KNN; ++j) {
        int m = ip[j];
        const float* yr = y + ((size_t)(b * NPTS) + m) * CO;
#pragma unroll
        for (int q = 0; q < NCH; ++q) {
            int c = l + 64 * q;
            float v = yr[c] + zv[q];
            hw[q][j] = v;
            float tt = v > 0.f ? v : v * SLOPE;
            float part = tt * av[q];
            part += __shfl_xor(part, 1);
            part += __shfl_xor(part, 2);
            lg[q][j] = part;
        }
    }
#pragma unroll
    for (int q = 0; q < NCH; ++q) {
        float mx = -FLT_MAX;
#pragma unroll
        for (int j = 0; j < KNN; ++j) mx = fmaxf(mx, lg[q][j]);
        float s = 0.f;
#pragma unroll
        for (int j = 0; j < KNN; ++j) { float e = expf(lg[q][j] - mx); lg[q][j] = e; s += e; }
        float inv = 1.f / s;
        float o = 0.f;
#pragma unroll
        for (int j = 0; j < KNN; ++j) o = fmaf(lg[q][j] * inv, hw[q][j], o);
        o = o > 0.f ? o : o * SLOPE;
        int c = l + 64 * q;
        hout[(size_t)p * CO + c] = o;
    }
}

// ---------------- BN stats, deterministic two-stage ----------------
__global__ void bnstatA_kernel(const float* __restrict__ h, float* __restrict__ part, int CO) {
    __shared__ float s1[256], s2[256];
    int g = blockIdx.x, t = threadIdx.x;
    int c = t & (CO - 1), sub = t / CO;
    int nsub = 256 / CO;
    const int ppb = BN / 64;                  // 256 points per block
    float a1 = 0.f, a2 = 0.f;
    for (int i = 0; i < ppb / nsub; ++i) {
        int p = g * ppb + sub + i * nsub;
        float v = h[(size_t)p * CO + c];
        a1 += v; a2 = fmaf(v, v, a2);
    }
    s1[t] = a1; s2[t] = a2;
    __syncthreads();
    if (sub == 0) {
        for (int k = 1; k < nsub; ++k) { a1 += s1[k * CO + c]; a2 += s2[k * CO + c]; }
        part[(size_t)g * CO + c]        = a1;
        part[(size_t)(64 + g) * CO + c] = a2;
    }
}

__global__ void bnstatB_kernel(const float* __restrict__ part, float* __restrict__ mu,
                               float* __restrict__ rstd, int CO) {
    int c = threadIdx.x;
    float s1 = 0.f, s2 = 0.f;
    for (int g = 0; g < 64; ++g) { s1 += part[(size_t)g * CO + c]; s2 += part[(size_t)(64 + g) * CO + c]; }
    float m   = s1 / (float)BN;
    float var = s2 / (float)BN - m * m;
    mu[c]   = m;
    rstd[c] = 1.f / sqrtf(var + BNEPS);
}

// ---------------- BN apply + leaky + transpose to (B,C,N) ----------------
template<int CO>
__global__ __launch_bounds__(256) void bnapply_kernel(const float* __restrict__ h,
                                                      const float* __restrict__ mu,
                                                      const float* __restrict__ rstd,
                                                      const float* __restrict__ gamma,
                                                      const float* __restrict__ beta,
                                                      float* __restrict__ xout) {
    __shared__ float tile[64][CO + 1];
    int g  = blockIdx.x;
    int p0 = g * 64;
    int b  = p0 >> 11, n0 = p0 & (NPTS - 1);
    int t  = threadIdx.x;
    for (int fi = t; fi < 64 * CO; fi += 256) {
        int pt = fi / CO, c = fi % CO;
        tile[pt][c] = h[(size_t)(p0 + pt) * CO + c];
    }
    __syncthreads();
    for (int fi = t; fi < 64 * CO; fi += 256) {
        int c = fi >> 6, nn = fi & 63;
        float v = tile[nn][c];
        v = (v - mu[c]) * rstd[c] * gamma[c] + beta[c];
        v = v > 0.f ? v : v * SLOPE;
        xout[((size_t)b * CO + c) * NPTS + n0 + nn] = v;
    }
}

// ---------------- host ----------------
static void run_layer(const float* xin, const float* W, const float* a,
                      const float* gm, const float* bt, float* xout, int C, int CO,
                      float* xx, int* idx, float* y, float* z, float* h,
                      float* part, float* mu, float* rstd, hipStream_t stream) {
    xx_kernel<<<BN / 256, 256, 0, stream>>>(xin, xx, C);
    if (C == 3)
        knn13_kernel<3><<<BATCH * 128, 256, 0, stream>>>(xin, xx, idx);
    else
        knn13_kernel<64><<<BATCH * 128, 256, 0, stream>>>(xin, xx, idx);
    proj_kernel<<<BN, CO, 0, stream>>>(xin, W, y, z, C, CO);
    if (CO == 64)
        attn_kernel<64><<<BN / 4, 256, 0, stream>>>(y, z, idx, a, h);
    else
        attn_kernel<128><<<BN / 4, 256, 0, stream>>>(y, z, idx, a, h);
    bnstatA_kernel<<<64, 256, 0, stream>>>(h, part, CO);
    bnstatB_kernel<<<1, CO, 0, stream>>>(part, mu, rstd, CO);
    if (CO == 64)
        bnapply_kernel<64><<<BN / 64, 256, 0, stream>>>(h, mu, rstd, gm, bt, xout);
    else
        bnapply_kernel<128><<<BN / 64, 256, 0, stream>>>(h, mu, rstd, gm, bt, xout);
}

extern "C" void kernel_launch(void* const* d_in, const int* in_sizes, int n_in,
                              void* d_out, int out_size, void* d_ws, size_t ws_size,
                              hipStream_t stream) {
    const float* x  = (const float*)d_in[0];
    const float* W[3]  = {(const float*)d_in[1], (const float*)d_in[5], (const float*)d_in[9]};
    const float* a[3]  = {(const float*)d_in[2], (const float*)d_in[6], (const float*)d_in[10]};
    const float* gm[3] = {(const float*)d_in[3], (const float*)d_in[7], (const float*)d_in[11]};
    const float* bt[3] = {(const float*)d_in[4], (const float*)d_in[8], (const float*)d_in[12]};

    char* base = (char*)d_ws;
    size_t off = 0;
    auto carve = [&](size_t bytes) -> void* {
        void* r = base + off;
        off = (off + bytes + 255) & ~(size_t)255;
        return r;
    };
    float* xx   = (float*)carve((size_t)BN * sizeof(float));
    int*   idx  = (int*)  carve((size_t)BN * KNN * sizeof(int));
    float* y    = (float*)carve((size_t)BN * 128 * sizeof(float));
    float* z    = (float*)carve((size_t)BN * 128 * sizeof(float));
    float* h    = (float*)carve((size_t)BN * 128 * sizeof(float));
    float* part = (float*)carve((size_t)128 * 128 * sizeof(float));
    float* mu   = (float*)carve(128 * sizeof(float));
    float* rstd = (float*)carve(128 * sizeof(float));
    float* x1   = (float*)carve((size_t)BATCH * 64 * NPTS * sizeof(float));
    float* x2   = (float*)carve((size_t)BATCH * 64 * NPTS * sizeof(float));
    float* out  = (float*)d_out;

    run_layer(x,  W[0], a[0], gm[0], bt[0], x1,  3,  64, xx, idx, y, z, h, part, mu, rstd, stream);
    run_layer(x1, W[1], a[1], gm[1], bt[1], x2,  64, 64, xx, idx, y, z, h, part, mu, rstd, stream);
    run_layer(x2, W[2], a[2], gm[2], bt[2], out, 64, 128, xx, idx, y, z, h, part, mu, rstd, stream);
}

// Round 15
// 1314.215 us; speedup vs baseline: 1.0024x; 1.0024x over previous
//
#include <hip/hip_runtime.h>
#include <float.h>
#include <math.h>

#define BATCH 8
#define NPTS  2048
#define KNN   20
#define BN    (BATCH*NPTS)
#define SLOPE 0.2f
#define BNEPS 1e-5f

// ---------------- xx: per-point squared norm ----------------
__global__ void xx_kernel(const float* __restrict__ x, float* __restrict__ xx, int C) {
    int p = blockIdx.x * 256 + threadIdx.x;           // p in [0, BN)
    int b = p >> 11, n = p & (NPTS - 1);
    const float* xb = x + (size_t)b * C * NPTS;
    float s = 0.f;
    for (int c = 0; c < C; ++c) { float v = xb[(size_t)c * NPTS + n]; s = fmaf(v, v, s); }
    xx[p] = s;
}

// async global->LDS, 16B per lane (dest linear in lane order; proven knn6-13)
__device__ __forceinline__ void gload_lds16(const float* g, float* l) {
    __builtin_amdgcn_global_load_lds(
        (const __attribute__((address_space(1))) void*)g,
        (__attribute__((address_space(3))) void*)l, 16, 0, 0);
}

// ---------------- kNN v14: knn13 semantics on knn7 chassis ----------------
// Phase A (cols 0..511, the sample knn13 validated CAP=192 against): knn7's
// geometry (CHUNK=128, dt redistribute, thr filter, gload_lds) with a
// VALUE-ONLY bubble -> 8-way merge -> Trow = exact T20(sample) >= row T20.
// Phase B: recompute all 16 chunks with the bitwise-identical fmaf chain,
// candidate columns read straight from global (L1-served), ZERO barriers;
// v <= Trow -> rare pool append (gated body ~8 instr, not a ~100-instr
// bubble -- the wave gate can't be lowered, so shrink what it gates).
// Emit: lex (v,i) rank over pool == lax.top_k order (knn13-proven).
template<int C>
__global__ __launch_bounds__(256, 2) void knn14_kernel(const float* __restrict__ x,
                                                       const float* __restrict__ xx,
                                                       int* __restrict__ idx) {
    constexpr int ROWS = 32, CHUNK = 128;
    constexpr int SCH  = 4;                    // sample chunks: cols 0..511
    constexpr int NCH  = NPTS / CHUNK;         // 16 full chunks
    constexpr int CAP  = 192;
    constexpr int NST  = (C * 32 + 255) / 256; // gload calls/thread (phase A)

    __shared__ __align__(16) float xrT[C][36];
    __shared__ float thrG[8][32];
    __shared__ float Trow[ROWS];
    __shared__ int   cnt[ROWS];
    __shared__ __align__(16) union UU {
        struct {
            union { float xc[C][CHUNK]; float Lv[8][KNN][ROWS]; } xl;
            float dt[ROWS][129];
        } a;
        struct { float pv[ROWS][CAP + 1]; unsigned short pj[ROWS][CAP + 2]; } b;
    } u;

    const int t  = threadIdx.x;
    const int b  = blockIdx.x >> 6;           // 64 tiles per batch
    const int r0 = (blockIdx.x & 63) * ROWS;
    const float* xb  = x  + (size_t)b * C * NPTS;
    const float* xxb = xx + (size_t)b * NPTS;

    const int ty = t >> 5, tx = t & 31;       // compute: rows 4ty..+3, cols 4tx..+3
    const int ty4 = ty * 4, tx4 = tx * 4;     // select : row tx, group ty

    // ---- prologue: stage xrT, init thrG, async-load chunk 0 ----
    for (int f = t; f < ROWS * C; f += 256) {
        int r = f & 31, c = f >> 5;
        xrT[c][r] = xb[(size_t)c * NPTS + r0 + r];
    }
    thrG[ty][tx] = FLT_MAX;
#pragma unroll
    for (int k = 0; k < NST; ++k) {
        int i = t + 256 * k;
        if (i < C * 32) {
            int c = i >> 5, j = (i & 31) * 4;
            gload_lds16(xb + (size_t)c * NPTS + j, &u.a.xl.xc[0][0] + (size_t)i * 4);
        }
    }

    float lv[KNN];
#pragma unroll
    for (int s = 0; s < KNN; ++s) lv[s] = FLT_MAX;

    __syncthreads();                          // drains vmcnt -> chunk 0 in xc

    // ---------------- phase A: value-only top-20 over sample ----------------
    for (int ch = 0; ch < SCH; ++ch) {
        int j0 = ch * CHUNK;

        float4 a0 = {0,0,0,0}, a1 = {0,0,0,0}, a2 = {0,0,0,0}, a3 = {0,0,0,0};
#pragma unroll 4
        for (int c = 0; c < C; ++c) {
            float4 rv = *(const float4*)&xrT[c][ty4];
            float4 cv = *(const float4*)&u.a.xl.xc[c][tx4];
            a0.x = fmaf(rv.x, cv.x, a0.x); a0.y = fmaf(rv.x, cv.y, a0.y);
            a0.z = fmaf(rv.x, cv.z, a0.z); a0.w = fmaf(rv.x, cv.w, a0.w);
            a1.x = fmaf(rv.y, cv.x, a1.x); a1.y = fmaf(rv.y, cv.y, a1.y);
            a1.z = fmaf(rv.y, cv.z, a1.z); a1.w = fmaf(rv.y, cv.w, a1.w);
            a2.x = fmaf(rv.z, cv.x, a2.x); a2.y = fmaf(rv.z, cv.y, a2.y);
            a2.z = fmaf(rv.z, cv.z, a2.z); a2.w = fmaf(rv.z, cv.w, a2.w);
            a3.x = fmaf(rv.w, cv.x, a3.x); a3.y = fmaf(rv.w, cv.y, a3.y);
            a3.z = fmaf(rv.w, cv.z, a3.z); a3.w = fmaf(rv.w, cv.w, a3.w);
        }
        {
            float4 xq = *(const float4*)&xxb[j0 + tx4];
            u.a.dt[ty4 + 0][tx4 + 0] = xq.x - 2.f * a0.x;
            u.a.dt[ty4 + 0][tx4 + 1] = xq.y - 2.f * a0.y;
            u.a.dt[ty4 + 0][tx4 + 2] = xq.z - 2.f * a0.z;
            u.a.dt[ty4 + 0][tx4 + 3] = xq.w - 2.f * a0.w;
            u.a.dt[ty4 + 1][tx4 + 0] = xq.x - 2.f * a1.x;
            u.a.dt[ty4 + 1][tx4 + 1] = xq.y - 2.f * a1.y;
            u.a.dt[ty4 + 1][tx4 + 2] = xq.z - 2.f * a1.z;
            u.a.dt[ty4 + 1][tx4 + 3] = xq.w - 2.f * a1.w;
            u.a.dt[ty4 + 2][tx4 + 0] = xq.x - 2.f * a2.x;
            u.a.dt[ty4 + 2][tx4 + 1] = xq.y - 2.f * a2.y;
            u.a.dt[ty4 + 2][tx4 + 2] = xq.z - 2.f * a2.z;
            u.a.dt[ty4 + 2][tx4 + 3] = xq.w - 2.f * a2.w;
            u.a.dt[ty4 + 3][tx4 + 0] = xq.x - 2.f * a3.x;
            u.a.dt[ty4 + 3][tx4 + 1] = xq.y - 2.f * a3.y;
            u.a.dt[ty4 + 3][tx4 + 2] = xq.z - 2.f * a3.z;
            u.a.dt[ty4 + 3][tx4 + 3] = xq.w - 2.f * a3.w;
        }
        __syncthreads();                      // dt visible; xc reads complete

        if (ch + 1 < SCH) {
            int j0n = j0 + CHUNK;
#pragma unroll
            for (int k = 0; k < NST; ++k) {
                int i = t + 256 * k;
                if (i < C * 32) {
                    int c = i >> 5, j = (i & 31) * 4;
                    gload_lds16(xb + (size_t)c * NPTS + j0n + j,
                                &u.a.xl.xc[0][0] + (size_t)i * 4);
                }
            }
        }

        {
            int r = tx;
            float thr = thrG[0][r];
#pragma unroll
            for (int g = 1; g < 8; ++g) thr = fminf(thr, thrG[g][r]);
            const float* drow = &u.a.dt[r][ty * 16];
#pragma unroll
            for (int m = 0; m < 16; ++m) {
                float v = drow[m];
                if (v < lv[KNN - 1] && v <= thr) {
                    lv[KNN - 1] = v;
#pragma unroll
                    for (int s = KNN - 1; s > 0; --s) {
                        float lo = fminf(lv[s - 1], lv[s]);
                        float hi = fmaxf(lv[s - 1], lv[s]);
                        lv[s - 1] = lo; lv[s] = hi;
                    }
                }
            }
        }
        thrG[ty][tx] = lv[KNN - 1];
        __syncthreads();                      // drains gload; scan done
    }

    // dump value lists (xc dead) + 8-way merge -> Trow = exact T20(sample)
    {
        int r = tx, g = ty;
#pragma unroll
        for (int s = 0; s < KNN; ++s) u.a.xl.Lv[g][s][r] = lv[s];
    }
    __syncthreads();
    if (t < ROWS) {
        float hv[8]; int pp[8];
#pragma unroll
        for (int g = 0; g < 8; ++g) { pp[g] = 0; hv[g] = u.a.xl.Lv[g][0][t]; }
        float T = FLT_MAX;
        for (int o = 0; o < KNN; ++o) {
            float bv = hv[0]; int bg = 0;
#pragma unroll
            for (int g = 1; g < 8; ++g) if (hv[g] < bv) { bv = hv[g]; bg = g; }
            T = bv;
            ++pp[bg];
            hv[bg] = (pp[bg] < KNN) ? u.a.xl.Lv[bg][pp[bg]][t] : FLT_MAX;
        }
        Trow[t] = T;
        cnt[t]  = 0;
    }
    __syncthreads();                          // Trow/cnt ready; Lv/dt dead

    // ---------------- phase B: barrier-free full scan + pool append --------
    const float T0 = Trow[ty4 + 0], T1 = Trow[ty4 + 1];
    const float T2 = Trow[ty4 + 2], T3 = Trow[ty4 + 3];

    for (int ch = 0; ch < NCH; ++ch) {
        int j0 = ch * CHUNK;
        float4 a0 = {0,0,0,0}, a1 = {0,0,0,0}, a2 = {0,0,0,0}, a3 = {0,0,0,0};
#pragma unroll 4
        for (int c = 0; c < C; ++c) {
            float4 rv = *(const float4*)&xrT[c][ty4];
            float4 cv = *(const float4*)(xb + (size_t)c * NPTS + j0 + tx4);
            a0.x = fmaf(rv.x, cv.x, a0.x); a0.y = fmaf(rv.x, cv.y, a0.y);
            a0.z = fmaf(rv.x, cv.z, a0.z); a0.w = fmaf(rv.x, cv.w, a0.w);
            a1.x = fmaf(rv.y, cv.x, a1.x); a1.y = fmaf(rv.y, cv.y, a1.y);
            a1.z = fmaf(rv.y, cv.z, a1.z); a1.w = fmaf(rv.y, cv.w, a1.w);
            a2.x = fmaf(rv.z, cv.x, a2.x); a2.y = fmaf(rv.z, cv.y, a2.y);
            a2.z = fmaf(rv.z, cv.z, a2.z); a2.w = fmaf(rv.z, cv.w, a2.w);
            a3.x = fmaf(rv.w, cv.x, a3.x); a3.y = fmaf(rv.w, cv.y, a3.y);
            a3.z = fmaf(rv.w, cv.z, a3.z); a3.w = fmaf(rv.w, cv.w, a3.w);
        }
        float4 xq = *(const float4*)&xxb[j0 + tx4];

#define KNN14_EMIT(vv, ri, Tri, cj)                                        \
        {                                                                  \
            float _v = (vv);                                               \
            if (_v <= (Tri)) {                                             \
                int sl = atomicAdd(&cnt[ty4 + (ri)], 1);                   \
                if (sl < CAP) {                                            \
                    u.b.pv[ty4 + (ri)][sl] = _v;                           \
                    u.b.pj[ty4 + (ri)][sl] = (unsigned short)(j0 + tx4 + (cj)); \
                }                                                          \
            }                                                              \
        }
        KNN14_EMIT(xq.x - 2.f * a0.x, 0, T0, 0)
        KNN14_EMIT(xq.y - 2.f * a0.y, 0, T0, 1)
        KNN14_EMIT(xq.z - 2.f * a0.z, 0, T0, 2)
        KNN14_EMIT(xq.w - 2.f * a0.w, 0, T0, 3)
        KNN14_EMIT(xq.x - 2.f * a1.x, 1, T1, 0)
        KNN14_EMIT(xq.y - 2.f * a1.y, 1, T1, 1)
        KNN14_EMIT(xq.z - 2.f * a1.z, 1, T1, 2)
        KNN14_EMIT(xq.w - 2.f * a1.w, 1, T1, 3)
        KNN14_EMIT(xq.x - 2.f * a2.x, 2, T2, 0)
        KNN14_EMIT(xq.y - 2.f * a2.y, 2, T2, 1)
        KNN14_EMIT(xq.z - 2.f * a2.z, 2, T2, 2)
        KNN14_EMIT(xq.w - 2.f * a2.w, 2, T2, 3)
        KNN14_EMIT(xq.x - 2.f * a3.x, 3, T3, 0)
        KNN14_EMIT(xq.y - 2.f * a3.y, 3, T3, 1)
        KNN14_EMIT(xq.z - 2.f * a3.z, 3, T3, 2)
        KNN14_EMIT(xq.w - 2.f * a3.w, 3, T3, 3)
#undef KNN14_EMIT
    }
    __syncthreads();                          // pool complete

    // ---------------- rank emit: lex (v,i) rank == lax.top_k order ---------
    {
        int rr = t & 31, role = t >> 5;
        int P = min(cnt[rr], CAP);
        int* op = idx + (size_t)(b * NPTS + r0 + rr) * KNN;
        for (int s = role; s < P; s += 8) {
            float vs = u.b.pv[rr][s]; int js = u.b.pj[rr][s];
            int rank = 0;
            for (int q = 0; q < P; ++q) {
                float vq = u.b.pv[rr][q]; int jq = u.b.pj[rr][q];
                rank += (vq < vs || (vq == vs && jq < js)) ? 1 : 0;
            }
            if (rank < KNN) op[rank] = js;
        }
    }
}

// ---------------- projection: y = x@Wtop, z = x@(Wbot-Wtop) ----------------
__global__ void proj_kernel(const float* __restrict__ x, const float* __restrict__ W,
                            float* __restrict__ y, float* __restrict__ z, int C, int Cout) {
    int p = blockIdx.x;
    int b = p >> 11, n = p & (NPTS - 1);
    int j = threadIdx.x;                      // j < Cout
    __shared__ float xc[64];
    if (j < C) xc[j] = x[(size_t)b * C * NPTS + (size_t)j * NPTS + n];
    __syncthreads();
    float sy = 0.f, sz = 0.f;
    for (int c = 0; c < C; ++c) {
        float xv = xc[c];
        float wt = W[c * Cout + j];
        float wb = W[(C + c) * Cout + j];
        sy = fmaf(xv, wt, sy);
        sz = fmaf(xv, wb - wt, sz);
    }
    y[(size_t)p * Cout + j] = sy;
    z[(size_t)p * Cout + j] = sz;
}

// ---------------- fused attention: one wave per point ----------------
template<int CO>
__global__ __launch_bounds__(256) void attn_kernel(const float* __restrict__ y,
                                                   const float* __restrict__ z,
                                                   const int* __restrict__ idx,
                                                   const float* __restrict__ a,
                                                   float* __restrict__ hout) {
    constexpr int NCH = CO / 64;
    constexpr int H   = CO / 4;
    int wv = threadIdx.x >> 6;
    int l  = threadIdx.x & 63;
    int p  = blockIdx.x * 4 + wv;             // b*N + n
    int b  = p >> 11;
    float hw[NCH][KNN], lg[NCH][KNN], zv[NCH], av[NCH];
#pragma unroll
    for (int q = 0; q < NCH; ++q) {
        int c = l + 64 * q;
        zv[q] = z[(size_t)p * CO + c];
        av[q] = a[(c & 3) * H + (c >> 2)];
    }
    const int* ip = idx + (size_t)p * KNN;
#pragma unroll
    for (int j = 0; j < KNN; ++j) {
        int m = ip[j];
        const float* yr = y + ((size_t)(b * NPTS) + m) * CO;
#pragma unroll
        for (int q = 0; q < NCH; ++q) {
            int c = l + 64 * q;
            float v = yr[c] + zv[q];
            hw[q][j] = v;
            float tt = v > 0.f ? v : v * SLOPE;
            float part = tt * av[q];
            part += __shfl_xor(part, 1);
            part += __shfl_xor(part, 2);
            lg[q][j] = part;
        }
    }
#pragma unroll
    for (int q = 0; q < NCH; ++q) {
        float mx = -FLT_MAX;
#pragma unroll
        for (int j = 0; j < KNN; ++j) mx = fmaxf(mx, lg[q][j]);
        float s = 0.f;
#pragma unroll
        for (int j = 0; j < KNN; ++j) { float e = expf(lg[q][j] - mx); lg[q][j] = e; s += e; }
        float inv = 1.f / s;
        float o = 0.f;
#pragma unroll
        for (int j = 0; j < KNN; ++j) o = fmaf(lg[q][j] * inv, hw[q][j], o);
        o = o > 0.f ? o : o * SLOPE;
        int c = l + 64 * q;
        hout[(size_t)p * CO + c] = o;
    }
}

// ---------------- BN stats, deterministic two-stage ----------------
__global__ void bnstatA_kernel(const float* __restrict__ h, float* __restrict__ part, int CO) {
    __shared__ float s1[256], s2[256];
    int g = blockIdx.x, t = threadIdx.x;
    int c = t & (CO - 1), sub = t / CO;
    int nsub = 256 / CO;
    const int ppb = BN / 64;                  // 256 points per block
    float a1 = 0.f, a2 = 0.f;
    for (int i = 0; i < ppb / nsub; ++i) {
        int p = g * ppb + sub + i * nsub;
        float v = h[(size_t)p * CO + c];
        a1 += v; a2 = fmaf(v, v, a2);
    }
    s1[t] = a1; s2[t] = a2;
    __syncthreads();
    if (sub == 0) {
        for (int k = 1; k < nsub; ++k) { a1 += s1[k * CO + c]; a2 += s2[k * CO + c]; }
        part[(size_t)g * CO + c]        = a1;
        part[(size_t)(64 + g) * CO + c] = a2;
    }
}

__global__ void bnstatB_kernel(const float* __restrict__ part, float* __restrict__ mu,
                               float* __restrict__ rstd, int CO) {
    int c = threadIdx.x;
    float s1 = 0.f, s2 = 0.f;
    for (int g = 0; g < 64; ++g) { s1 += part[(size_t)g * CO + c]; s2 += part[(size_t)(64 + g) * CO + c]; }
    float m   = s1 / (float)BN;
    float var = s2 / (float)BN - m * m;
    mu[c]   = m;
    rstd[c] = 1.f / sqrtf(var + BNEPS);
}

// ---------------- BN apply + leaky + transpose to (B,C,N) ----------------
template<int CO>
__global__ __launch_bounds__(256) void bnapply_kernel(const float* __restrict__ h,
                                                      const float* __restrict__ mu,
                                                      const float* __restrict__ rstd,
                                                      const float* __restrict__ gamma,
                                                      const float* __restrict__ beta,
                                                      float* __restrict__ xout) {
    __shared__ float tile[64][CO + 1];
    int g  = blockIdx.x;
    int p0 = g * 64;
    int b  = p0 >> 11, n0 = p0 & (NPTS - 1);
    int t  = threadIdx.x;
    for (int fi = t; fi < 64 * CO; fi += 256) {
        int pt = fi / CO, c = fi % CO;
        tile[pt][c] = h[(size_t)(p0 + pt) * CO + c];
    }
    __syncthreads();
    for (int fi = t; fi < 64 * CO; fi += 256) {
        int c = fi >> 6, nn = fi & 63;
        float v = tile[nn][c];
        v = (v - mu[c]) * rstd[c] * gamma[c] + beta[c];
        v = v > 0.f ? v : v * SLOPE;
        xout[((size_t)b * CO + c) * NPTS + n0 + nn] = v;
    }
}

// ---------------- host ----------------
static void run_layer(const float* xin, const float* W, const float* a,
                      const float* gm, const float* bt, float* xout, int C, int CO,
                      float* xx, int* idx, float* y, float* z, float* h,
                      float* part, float* mu, float* rstd, hipStream_t stream) {
    xx_kernel<<<BN / 256, 256, 0, stream>>>(xin, xx, C);
    if (C == 3)
        knn14_kernel<3><<<BATCH * 64, 256, 0, stream>>>(xin, xx, idx);
    else
        knn14_kernel<64><<<BATCH * 64, 256, 0, stream>>>(xin, xx, idx);
    proj_kernel<<<BN, CO, 0, stream>>>(xin, W, y, z, C, CO);
    if (CO == 64)
        attn_kernel<64><<<BN / 4, 256, 0, stream>>>(y, z, idx, a, h);
    else
        attn_kernel<128><<<BN / 4, 256, 0, stream>>>(y, z, idx, a, h);
    bnstatA_kernel<<<64, 256, 0, stream>>>(h, part, CO);
    bnstatB_kernel<<<1, CO, 0, stream>>>(part, mu, rstd, CO);
    if (CO == 64)
        bnapply_kernel<64><<<BN / 64, 256, 0, stream>>>(h, mu, rstd, gm, bt, xout);
    else
        bnapply_kernel<128><<<BN / 64, 256, 0, stream>>>(h, mu, rstd, gm, bt, xout);
}

extern "C" void kernel_launch(void* const* d_in, const int* in_sizes, int n_in,
                              void* d_out, int out_size, void* d_ws, size_t ws_size,
                              hipStream_t stream) {
    const float* x  = (const float*)d_in[0];
    const float* W[3]  = {(const float*)d_in[1], (const float*)d_in[5], (const float*)d_in[9]};
    const float* a[3]  = {(const float*)d_in[2], (const float*)d_in[6], (const float*)d_in[10]};
    const float* gm[3] = {(const float*)d_in[3], (const float*)d_in[7], (const float*)d_in[11]};
    const float* bt[3] = {(const float*)d_in[4], (const float*)d_in[8], (const float*)d_in[12]};

    char* base = (char*)d_ws;
    size_t off = 0;
    auto carve = [&](size_t bytes) -> void* {
        void* r = base + off;
        off = (off + bytes + 255) & ~(size_t)255;
        return r;
    };
    float* xx   = (float*)carve((size_t)BN * sizeof(float));
    int*   idx  = (int*)  carve((size_t)BN * KNN * sizeof(int));
    float* y    = (float*)carve((size_t)BN * 128 * sizeof(float));
    float* z    = (float*)carve((size_t)BN * 128 * sizeof(float));
    float* h    = (float*)carve((size_t)BN * 128 * sizeof(float));
    float* part = (float*)carve((size_t)128 * 128 * sizeof(float));
    float* mu   = (float*)carve(128 * sizeof(float));
    float* rstd = (float*)carve(128 * sizeof(float));
    float* x1   = (float*)carve((size_t)BATCH * 64 * NPTS * sizeof(float));
    float* x2   = (float*)carve((size_t)BATCH * 64 * NPTS * sizeof(float));
    float* out  = (float*)d_out;

    run_layer(x,  W[0], a[0], gm[0], bt[0], x1,  3,  64, xx, idx, y, z, h, part, mu, rstd, stream);
    run_layer(x1, W[1], a[1], gm[1], bt[1], x2,  64, 64, xx, idx, y, z, h, part, mu, rstd, stream);
    run_layer(x2, W[2], a[2], gm[2], bt[2], out, 64, 128, xx, idx, y, z, h, part, mu, rstd, stream);
}

// Round 16
// 751.705 us; speedup vs baseline: 1.7524x; 1.7483x over previous
//
#include <hip/hip_runtime.h>
#include <float.h>
#include <math.h>

#define BATCH 8
#define NPTS  2048
#define KNN   20
#define BN    (BATCH*NPTS)
#define SLOPE 0.2f
#define BNEPS 1e-5f

// ---------------- xx: per-point squared norm ----------------
__global__ void xx_kernel(const float* __restrict__ x, float* __restrict__ xx, int C) {
    int p = blockIdx.x * 256 + threadIdx.x;           // p in [0, BN)
    int b = p >> 11, n = p & (NPTS - 1);
    const float* xb = x + (size_t)b * C * NPTS;
    float s = 0.f;
    for (int c = 0; c < C; ++c) { float v = xb[(size_t)c * NPTS + n]; s = fmaf(v, v, s); }
    xx[p] = s;
}

// async global->LDS, 16B per lane (dest linear in lane order; verified knn6)
__device__ __forceinline__ void gload_lds16(const float* g, float* l) {
    __builtin_amdgcn_global_load_lds(
        (const __attribute__((address_space(1))) void*)g,
        (__attribute__((address_space(3))) void*)l, 16, 0, 0);
}

// ---------------- kNN v7: champion engine (754.8us total, R8) -------------
// Direct branchy insert (A/B: deferred pop-loop = 810us, direct = 216us),
// shared-row threshold (exact: v > min_g(partner 20th) provably not in
// top-20), gload_lds staging, dt[32][129] conflict-free reads.
// 9 designs bracket this at 214-216us/dispatch invariant to FMA load,
// occupancy, visits/thread, barriers -> issue-throughput plateau.
template<int C>
__global__ __launch_bounds__(256, 2) void knn7_kernel(const float* __restrict__ x,
                                                      const float* __restrict__ xx,
                                                      int* __restrict__ idx) {
    constexpr int ROWS = 32, CHUNK = 128, NCH = NPTS / CHUNK;   // 16 chunks
    constexpr int NST  = (C * 32 + 255) / 256;                  // gload calls/thread

    __shared__ __align__(16) float xrT[C][36];
    __shared__ float thrG[8][32];
    __shared__ __align__(16) union ULX {
        struct { float xc[C][CHUNK]; float dt[ROWS][129]; } s;    // 49280 B (C=64)
        struct { float v[8][KNN][ROWS]; int i[8][KNN][ROWS]; } L; // 40960 B
    } u;

    int t  = threadIdx.x;
    int b  = blockIdx.x >> 6;                 // 64 tiles per batch
    int r0 = (blockIdx.x & 63) * ROWS;
    const float* xb  = x  + (size_t)b * C * NPTS;
    const float* xxb = xx + (size_t)b * NPTS;

    int ty = t >> 5, tx = t & 31;             // compute: rows 4ty..+3, cols 4tx..+3
    int ty4 = ty * 4, tx4 = tx * 4;           // select : row tx, group ty (16 cols)

    // ---- prologue: stage xrT, init thrG, async-load chunk 0 ----
    for (int f = t; f < ROWS * C; f += 256) {
        int r = f & 31, c = f >> 5;
        xrT[c][r] = xb[(size_t)c * NPTS + r0 + r];
    }
    thrG[ty][tx] = FLT_MAX;
#pragma unroll
    for (int k = 0; k < NST; ++k) {
        int i = t + 256 * k;
        if (i < C * 32) {
            int c = i >> 5, j = (i & 31) * 4;
            gload_lds16(xb + (size_t)c * NPTS + j, &u.s.xc[0][0] + (size_t)i * 4);
        }
    }

    float lv[KNN]; int li[KNN];
#pragma unroll
    for (int s = 0; s < KNN; ++s) { lv[s] = FLT_MAX; li[s] = 0x7fffffff; }

    __syncthreads();                          // drains vmcnt -> chunk 0 in xc

    for (int ch = 0; ch < NCH; ++ch) {
        int j0 = ch * CHUNK;

        // ---- compute 4x4 s-values (s = xx_c - 2*inner) from LDS ----
        float4 a0 = {0,0,0,0}, a1 = {0,0,0,0}, a2 = {0,0,0,0}, a3 = {0,0,0,0};
#pragma unroll 4
        for (int c = 0; c < C; ++c) {
            float4 rv = *(const float4*)&xrT[c][ty4];
            float4 cv = *(const float4*)&u.s.xc[c][tx4];
            a0.x = fmaf(rv.x, cv.x, a0.x); a0.y = fmaf(rv.x, cv.y, a0.y);
            a0.z = fmaf(rv.x, cv.z, a0.z); a0.w = fmaf(rv.x, cv.w, a0.w);
            a1.x = fmaf(rv.y, cv.x, a1.x); a1.y = fmaf(rv.y, cv.y, a1.y);
            a1.z = fmaf(rv.y, cv.z, a1.z); a1.w = fmaf(rv.y, cv.w, a1.w);
            a2.x = fmaf(rv.z, cv.x, a2.x); a2.y = fmaf(rv.z, cv.y, a2.y);
            a2.z = fmaf(rv.z, cv.z, a2.z); a2.w = fmaf(rv.z, cv.w, a2.w);
            a3.x = fmaf(rv.w, cv.x, a3.x); a3.y = fmaf(rv.w, cv.y, a3.y);
            a3.z = fmaf(rv.w, cv.z, a3.z); a3.w = fmaf(rv.w, cv.w, a3.w);
        }
        {
            float4 xq = *(const float4*)&xxb[j0 + tx4];
            u.s.dt[ty4 + 0][tx4 + 0] = xq.x - 2.f * a0.x;
            u.s.dt[ty4 + 0][tx4 + 1] = xq.y - 2.f * a0.y;
            u.s.dt[ty4 + 0][tx4 + 2] = xq.z - 2.f * a0.z;
            u.s.dt[ty4 + 0][tx4 + 3] = xq.w - 2.f * a0.w;
            u.s.dt[ty4 + 1][tx4 + 0] = xq.x - 2.f * a1.x;
            u.s.dt[ty4 + 1][tx4 + 1] = xq.y - 2.f * a1.y;
            u.s.dt[ty4 + 1][tx4 + 2] = xq.z - 2.f * a1.z;
            u.s.dt[ty4 + 1][tx4 + 3] = xq.w - 2.f * a1.w;
            u.s.dt[ty4 + 2][tx4 + 0] = xq.x - 2.f * a2.x;
            u.s.dt[ty4 + 2][tx4 + 1] = xq.y - 2.f * a2.y;
            u.s.dt[ty4 + 2][tx4 + 2] = xq.z - 2.f * a2.z;
            u.s.dt[ty4 + 2][tx4 + 3] = xq.w - 2.f * a2.w;
            u.s.dt[ty4 + 3][tx4 + 0] = xq.x - 2.f * a3.x;
            u.s.dt[ty4 + 3][tx4 + 1] = xq.y - 2.f * a3.y;
            u.s.dt[ty4 + 3][tx4 + 2] = xq.z - 2.f * a3.z;
            u.s.dt[ty4 + 3][tx4 + 3] = xq.w - 2.f * a3.w;
        }
        __syncthreads();                      // dt visible; xc reads complete

        // ---- async-load next chunk into xc (latency hidden by scan) ----
        if (ch + 1 < NCH) {
            int j0n = j0 + CHUNK;
#pragma unroll
            for (int k = 0; k < NST; ++k) {
                int i = t + 256 * k;
                if (i < C * 32) {
                    int c = i >> 5, j = (i & 31) * 4;
                    gload_lds16(xb + (size_t)c * NPTS + j0n + j,
                                &u.s.xc[0][0] + (size_t)i * 4);
                }
            }
        }

        // ---- scan 16 candidates (row tx, cols ty*16..+15), direct insert ----
        {
            int r = tx;
            float thr = thrG[0][r];
#pragma unroll
            for (int g = 1; g < 8; ++g) thr = fminf(thr, thrG[g][r]);

            const float* drow = &u.s.dt[r][ty * 16];
#pragma unroll
            for (int m = 0; m < 16; ++m) {
                float v = drow[m];
                if (v < lv[KNN - 1] && v <= thr) {
                    lv[KNN - 1] = v; li[KNN - 1] = j0 + ty * 16 + m;
#pragma unroll
                    for (int s = KNN - 1; s > 0; --s) {
                        if (lv[s] < lv[s - 1]) {
                            float tv = lv[s]; lv[s] = lv[s - 1]; lv[s - 1] = tv;
                            int   ti = li[s]; li[s] = li[s - 1]; li[s - 1] = ti;
                        }
                    }
                }
            }
        }
        thrG[ty][tx] = lv[KNN - 1];           // publish local 20th for row tx
        __syncthreads();                      // drains vmcnt -> next xc ready
    }

    // ---- dump per-thread lists into union (xc/dt dead) ----
    {
        int r = tx, g = ty;
#pragma unroll
        for (int s = 0; s < KNN; ++s) { u.L.v[g][s][r] = lv[s]; u.L.i[g][s][r] = li[s]; }
    }
    __syncthreads();

    // ---- 8-way lex merge per row ----
    if (t < ROWS) {
        int r = t;
        float hv[8]; int hi[8]; int pp[8];
#pragma unroll
        for (int g = 0; g < 8; ++g) { pp[g] = 0; hv[g] = u.L.v[g][0][r]; hi[g] = u.L.i[g][0][r]; }
        int* op = idx + (size_t)(b * NPTS + r0 + r) * KNN;
        for (int o = 0; o < KNN; ++o) {
            float bv = hv[0]; int bi = hi[0]; int bg = 0;
#pragma unroll
            for (int g = 1; g < 8; ++g)
                if (hv[g] < bv || (hv[g] == bv && hi[g] < bi)) { bv = hv[g]; bi = hi[g]; bg = g; }
            op[o] = bi;
#pragma unroll
            for (int g = 0; g < 8; ++g)
                if (bg == g) {
                    ++pp[g];
                    bool ok = pp[g] < KNN;
                    int q = ok ? pp[g] : KNN - 1;
                    float nv = u.L.v[g][q][r]; int ni = u.L.i[g][q][r];
                    hv[g] = ok ? nv : FLT_MAX;
                    hi[g] = ok ? ni : 0x7fffffff;
                }
        }
    }
}

// ---------------- projection: y = x@Wtop, z = x@(Wbot-Wtop) ----------------
__global__ void proj_kernel(const float* __restrict__ x, const float* __restrict__ W,
                            float* __restrict__ y, float* __restrict__ z, int C, int Cout) {
    int p = blockIdx.x;
    int b = p >> 11, n = p & (NPTS - 1);
    int j = threadIdx.x;                      // j < Cout
    __shared__ float xc[64];
    if (j < C) xc[j] = x[(size_t)b * C * NPTS + (size_t)j * NPTS + n];
    __syncthreads();
    float sy = 0.f, sz = 0.f;
    for (int c = 0; c < C; ++c) {
        float xv = xc[c];
        float wt = W[c * Cout + j];
        float wb = W[(C + c) * Cout + j];
        sy = fmaf(xv, wt, sy);
        sz = fmaf(xv, wb - wt, sz);
    }
    y[(size_t)p * Cout + j] = sy;
    z[(size_t)p * Cout + j] = sz;
}

// ---------------- fused attention: one wave per point ----------------
template<int CO>
__global__ __launch_bounds__(256) void attn_kernel(const float* __restrict__ y,
                                                   const float* __restrict__ z,
                                                   const int* __restrict__ idx,
                                                   const float* __restrict__ a,
                                                   float* __restrict__ hout) {
    constexpr int NCH = CO / 64;
    constexpr int H   = CO / 4;
    int wv = threadIdx.x >> 6;
    int l  = threadIdx.x & 63;
    int p  = blockIdx.x * 4 + wv;             // b*N + n
    int b  = p >> 11;
    float hw[NCH][KNN], lg[NCH][KNN], zv[NCH], av[NCH];
#pragma unroll
    for (int q = 0; q < NCH; ++q) {
        int c = l + 64 * q;
        zv[q] = z[(size_t)p * CO + c];
        av[q] = a[(c & 3) * H + (c >> 2)];
    }
    const int* ip = idx + (size_t)p * KNN;
#pragma unroll
    for (int j = 0; j < KNN; ++j) {
        int m = ip[j];
        const float* yr = y + ((size_t)(b * NPTS) + m) * CO;
#pragma unroll
        for (int q = 0; q < NCH; ++q) {
            int c = l + 64 * q;
            float v = yr[c] + zv[q];
            hw[q][j] = v;
            float tt = v > 0.f ? v : v * SLOPE;
            float part = tt * av[q];
            part += __shfl_xor(part, 1);
            part += __shfl_xor(part, 2);
            lg[q][j] = part;
        }
    }
#pragma unroll
    for (int q = 0; q < NCH; ++q) {
        float mx = -FLT_MAX;
#pragma unroll
        for (int j = 0; j < KNN; ++j) mx = fmaxf(mx, lg[q][j]);
        float s = 0.f;
#pragma unroll
        for (int j = 0; j < KNN; ++j) { float e = expf(lg[q][j] - mx); lg[q][j] = e; s += e; }
        float inv = 1.f / s;
        float o = 0.f;
#pragma unroll
        for (int j = 0; j < KNN; ++j) o = fmaf(lg[q][j] * inv, hw[q][j], o);
        o = o > 0.f ? o : o * SLOPE;
        int c = l + 64 * q;
        hout[(size_t)p * CO + c] = o;
    }
}

// ---------------- BN stats, deterministic two-stage ----------------
__global__ void bnstatA_kernel(const float* __restrict__ h, float* __restrict__ part, int CO) {
    __shared__ float s1[256], s2[256];
    int g = blockIdx.x, t = threadIdx.x;
    int c = t & (CO - 1), sub = t / CO;
    int nsub = 256 / CO;
    const int ppb = BN / 64;                  // 256 points per block
    float a1 = 0.f, a2 = 0.f;
    for (int i = 0; i < ppb / nsub; ++i) {
        int p = g * ppb + sub + i * nsub;
        float v = h[(size_t)p * CO + c];
        a1 += v; a2 = fmaf(v, v, a2);
    }
    s1[t] = a1; s2[t] = a2;
    __syncthreads();
    if (sub == 0) {
        for (int k = 1; k < nsub; ++k) { a1 += s1[k * CO + c]; a2 += s2[k * CO + c]; }
        part[(size_t)g * CO + c]        = a1;
        part[(size_t)(64 + g) * CO + c] = a2;
    }
}

__global__ void bnstatB_kernel(const float* __restrict__ part, float* __restrict__ mu,
                               float* __restrict__ rstd, int CO) {
    int c = threadIdx.x;
    float s1 = 0.f, s2 = 0.f;
    for (int g = 0; g < 64; ++g) { s1 += part[(size_t)g * CO + c]; s2 += part[(size_t)(64 + g) * CO + c]; }
    float m   = s1 / (float)BN;
    float var = s2 / (float)BN - m * m;
    mu[c]   = m;
    rstd[c] = 1.f / sqrtf(var + BNEPS);
}

// ---------------- BN apply + leaky + transpose to (B,C,N) ----------------
template<int CO>
__global__ __launch_bounds__(256) void bnapply_kernel(const float* __restrict__ h,
                                                      const float* __restrict__ mu,
                                                      const float* __restrict__ rstd,
                                                      const float* __restrict__ gamma,
                                                      const float* __restrict__ beta,
                                                      float* __restrict__ xout) {
    __shared__ float tile[64][CO + 1];
    int g  = blockIdx.x;
    int p0 = g * 64;
    int b  = p0 >> 11, n0 = p0 & (NPTS - 1);
    int t  = threadIdx.x;
    for (int fi = t; fi < 64 * CO; fi += 256) {
        int pt = fi / CO, c = fi % CO;
        tile[pt][c] = h[(size_t)(p0 + pt) * CO + c];
    }
    __syncthreads();
    for (int fi = t; fi < 64 * CO; fi += 256) {
        int c = fi >> 6, nn = fi & 63;
        float v = tile[nn][c];
        v = (v - mu[c]) * rstd[c] * gamma[c] + beta[c];
        v = v > 0.f ? v : v * SLOPE;
        xout[((size_t)b * CO + c) * NPTS + n0 + nn] = v;
    }
}

// ---------------- host ----------------
static void run_layer(const float* xin, const float* W, const float* a,
                      const float* gm, const float* bt, float* xout, int C, int CO,
                      float* xx, int* idx, float* y, float* z, float* h,
                      float* part, float* mu, float* rstd, hipStream_t stream) {
    xx_kernel<<<BN / 256, 256, 0, stream>>>(xin, xx, C);
    if (C == 3)
        knn7_kernel<3><<<BATCH * 64, 256, 0, stream>>>(xin, xx, idx);
    else
        knn7_kernel<64><<<BATCH * 64, 256, 0, stream>>>(xin, xx, idx);
    proj_kernel<<<BN, CO, 0, stream>>>(xin, W, y, z, C, CO);
    if (CO == 64)
        attn_kernel<64><<<BN / 4, 256, 0, stream>>>(y, z, idx, a, h);
    else
        attn_kernel<128><<<BN / 4, 256, 0, stream>>>(y, z, idx, a, h);
    bnstatA_kernel<<<64, 256, 0, stream>>>(h, part, CO);
    bnstatB_kernel<<<1, CO, 0, stream>>>(part, mu, rstd, CO);
    if (CO == 64)
        bnapply_kernel<64><<<BN / 64, 256, 0, stream>>>(h, mu, rstd, gm, bt, xout);
    else
        bnapply_kernel<128><<<BN / 64, 256, 0, stream>>>(h, mu, rstd, gm, bt, xout);
}

extern "C" void kernel_launch(void* const* d_in, const int* in_sizes, int n_in,
                              void* d_out, int out_size, void* d_ws, size_t ws_size,
                              hipStream_t stream) {
    const float* x  = (const float*)d_in[0];
    const float* W[3]  = {(const float*)d_in[1], (const float*)d_in[5], (const float*)d_in[9]};
    const float* a[3]  = {(const float*)d_in[2], (const float*)d_in[6], (const float*)d_in[10]};
    const float* gm[3] = {(const float*)d_in[3], (const float*)d_in[7], (const float*)d_in[11]};
    const float* bt[3] = {(const float*)d_in[4], (const float*)d_in[8], (const float*)d_in[12]};

    char* base = (char*)d_ws;
    size_t off = 0;
    auto carve = [&](size_t bytes) -> void* {
        void* r = base + off;
        off = (off + bytes + 255) & ~(size_t)255;
        return r;
    };
    float* xx   = (float*)carve((size_t)BN * sizeof(float));
    int*   idx  = (int*)  carve((size_t)BN * KNN * sizeof(int));
    float* y    = (float*)carve((size_t)BN * 128 * sizeof(float));
    float* z    = (float*)carve((size_t)BN * 128 * sizeof(float));
    float* h    = (float*)carve((size_t)BN * 128 * sizeof(float));
    float* part = (float*)carve((size_t)128 * 128 * sizeof(float));
    float* mu   = (float*)carve(128 * sizeof(float));
    float* rstd = (float*)carve(128 * sizeof(float));
    float* x1   = (float*)carve((size_t)BATCH * 64 * NPTS * sizeof(float));
    float* x2   = (float*)carve((size_t)BATCH * 64 * NPTS * sizeof(float));
    float* out  = (float*)d_out;

    run_layer(x,  W[0], a[0], gm[0], bt[0], x1,  3,  64, xx, idx, y, z, h, part, mu, rstd, stream);
    run_layer(x1, W[1], a[1], gm[1], bt[1], x2,  64, 64, xx, idx, y, z, h, part, mu, rstd, stream);
    run_layer(x2, W[2], a[2], gm[2], bt[2], out, 64, 128, xx, idx, y, z, h, part, mu, rstd, stream);
}